// Round 1
// baseline (170.272 us; speedup 1.0000x reference)
//
#include <hip/hip_runtime.h>
#include <math.h>

#define VB 28
#define LL 64
#define PAD_TOK 26
#define EOS_TOK 27

__device__ __forceinline__ float wave_red(float v) {
  #pragma unroll
  for (int o = 32; o > 0; o >>= 1) v += __shfl_down(v, o, 64);
  return v;
}

// ws layout (floats): 0 loss_sum, 1 mask_cnt, 2 consec, 3 mexp_cnt,
//                     4 kl_sum, 5 cls_sum, 6..33 vocab sums
__global__ __launch_bounds__(256) void vae_main(const float* __restrict__ x,
                                                const float* __restrict__ rec,
                                                float* __restrict__ ws,
                                                int nrows) {
  __shared__ float w_pow[64];
  __shared__ float red[4][32];
  const int lane = threadIdx.x & 63;
  const int wid  = threadIdx.x >> 6;
  if (threadIdx.x < 63) w_pow[threadIdx.x] = powf((float)(threadIdx.x + 1), 2.5f);
  __syncthreads();

  float loss_acc = 0.f, mask_cnt = 0.f, consec_acc = 0.f, mexp_cnt = 0.f;
  float vocab[VB];
  #pragma unroll
  for (int v = 0; v < VB; ++v) vocab[v] = 0.f;

  const int wave_id = blockIdx.x * 4 + wid;
  const int n_waves = gridDim.x * 4;

  for (int row = wave_id; row < nrows; row += n_waves) {
    const size_t base = ((size_t)row * LL + lane) * VB;
    const float4* xp = reinterpret_cast<const float4*>(x + base);
    const float4* rp = reinterpret_cast<const float4*>(rec + base);
    float r[VB];
    float best = -INFINITY, pt = 0.f;
    int tgt = 0;
    #pragma unroll
    for (int i = 0; i < 7; ++i) {
      float4 xq = xp[i];
      float4 rq = rp[i];
      r[i*4+0] = rq.x; r[i*4+1] = rq.y; r[i*4+2] = rq.z; r[i*4+3] = rq.w;
      if (xq.x > best) { best = xq.x; tgt = i*4+0; pt = rq.x; }
      if (xq.y > best) { best = xq.y; tgt = i*4+1; pt = rq.y; }
      if (xq.z > best) { best = xq.z; tgt = i*4+2; pt = rq.z; }
      if (xq.w > best) { best = xq.w; tgt = i*4+3; pt = rq.w; }
    }
    const float mask = (tgt != PAD_TOK) ? 1.f : 0.f;
    const float mexp = (tgt != PAD_TOK && tgt != EOS_TOK) ? 1.f : 0.f;
    loss_acc += -logf(fminf(fmaxf(pt, 1e-7f), 1.f)) * mask;
    mask_cnt += mask;
    mexp_cnt += mexp;
    #pragma unroll
    for (int v = 0; v < VB; ++v) vocab[v] += r[v] * mexp;

    // adjacent[j] = dot(recon[:,j], recon[:,j+1]), masked by target[j+1]!=PAD
    float adj = 0.f;
    #pragma unroll
    for (int v = 0; v < VB; ++v) adj += r[v] * __shfl_down(r[v], 1, 64);
    const int tgt_next = __shfl_down(tgt, 1, 64);
    adj = (lane < 63 && tgt_next != PAD_TOK) ? adj : 0.f;

    // sum over window lengths: len^2.5 * prod(adjacent[j..j+len-1])
    float p = adj;                 // len = 1, weight 1^2.5 = 1
    consec_acc += p;
    for (int k = 1; k < 63; ++k) {
      const float sh = __shfl_down(adj, k, 64);
      p = (lane < 63 - k) ? p * sh : 0.f;
      consec_acc += w_pow[k] * p;  // weight (k+1)^2.5
      if (__ballot(p != 0.f) == 0ull) break;   // all windows underflowed
    }
  }

  loss_acc   = wave_red(loss_acc);
  mask_cnt   = wave_red(mask_cnt);
  consec_acc = wave_red(consec_acc);
  mexp_cnt   = wave_red(mexp_cnt);
  #pragma unroll
  for (int v = 0; v < VB; ++v) vocab[v] = wave_red(vocab[v]);

  if (lane == 0) {
    red[wid][0] = loss_acc;
    red[wid][1] = mask_cnt;
    red[wid][2] = consec_acc;
    red[wid][3] = mexp_cnt;
    #pragma unroll
    for (int v = 0; v < VB; ++v) red[wid][4 + v] = vocab[v];
  }
  __syncthreads();
  if (threadIdx.x < 32) {
    const int j = threadIdx.x;
    const float s = red[0][j] + red[1][j] + red[2][j] + red[3][j];
    const int dst = (j < 4) ? j : (6 + (j - 4));
    atomicAdd(&ws[dst], s);
  }
}

__global__ __launch_bounds__(256) void vae_klcls(const float* __restrict__ zm,
                                                 const float* __restrict__ zlv,
                                                 const float* __restrict__ cs,
                                                 float* __restrict__ ws,
                                                 int nz, int nc) {
  __shared__ float red[4][2];
  const int lane = threadIdx.x & 63;
  const int wid  = threadIdx.x >> 6;
  const int gid = blockIdx.x * blockDim.x + threadIdx.x;
  const int stride = gridDim.x * blockDim.x;
  float kl = 0.f, cl = 0.f;
  for (int i = gid; i < nz; i += stride) {
    const float m = zm[i], lv = zlv[i];
    kl += 1.f + lv - m * m - expf(lv);
  }
  for (int i = gid; i < nc; i += stride) cl += logf(cs[i] + 1e-7f);
  kl = wave_red(kl);
  cl = wave_red(cl);
  if (lane == 0) { red[wid][0] = kl; red[wid][1] = cl; }
  __syncthreads();
  if (threadIdx.x < 2) {
    const float s = red[0][threadIdx.x] + red[1][threadIdx.x] +
                    red[2][threadIdx.x] + red[3][threadIdx.x];
    atomicAdd(&ws[4 + threadIdx.x], s);
  }
}

__global__ void vae_finalize(const float* __restrict__ ws, float* __restrict__ out,
                             float nz, float nc) {
  if (threadIdx.x == 0 && blockIdx.x == 0) {
    const float freqs[VB] = {0.0817f,0.0149f,0.0278f,0.0425f,0.127f,0.0223f,0.0202f,
      0.0609f,0.0697f,0.0015f,0.0077f,0.0403f,0.0241f,0.0675f,0.0751f,0.0193f,0.001f,
      0.0599f,0.0633f,0.0906f,0.0276f,0.0098f,0.0236f,0.0015f,0.0197f,0.0007f,0.f,0.f};
    const float rec_loss = ws[0] / ws[1];
    const float kl       = -0.5f * ws[4] / nz;
    const float cls      = -ws[5] / nc;
    const float inv_mexp = 1.f / ws[3];
    float fp = 0.f;
    #pragma unroll
    for (int v = 0; v < VB; ++v) fp += fmaxf(0.f, ws[6 + v] * inv_mexp - freqs[v]);
    out[0] = rec_loss + 0.1f * kl + 2.f * cls + 0.2f * ws[2] + 0.5f * fp;
  }
}

extern "C" void kernel_launch(void* const* d_in, const int* in_sizes, int n_in,
                              void* d_out, int out_size, void* d_ws, size_t ws_size,
                              hipStream_t stream) {
  const float* x   = (const float*)d_in[0];
  const float* rec = (const float*)d_in[1];
  const float* zm  = (const float*)d_in[2];
  const float* zlv = (const float*)d_in[3];
  const float* cs  = (const float*)d_in[4];
  float* out = (float*)d_out;
  float* ws  = (float*)d_ws;

  const int nz    = in_sizes[2];                 // B * LATENT
  const int nc    = in_sizes[4];                 // B
  const int nrows = in_sizes[0] / (LL * VB);     // B

  hipMemsetAsync(d_ws, 0, 64 * sizeof(float), stream);
  vae_main<<<1024, 256, 0, stream>>>(x, rec, ws, nrows);
  vae_klcls<<<128, 256, 0, stream>>>(zm, zlv, cs, ws, nz, nc);
  vae_finalize<<<1, 64, 0, stream>>>(ws, out, (float)nz, (float)nc);
}